// Round 4
// baseline (213.711 us; speedup 1.0000x reference)
//
#include <hip/hip_runtime.h>
#include <hip/hip_bf16.h>
#include <math.h>

#define BB 128
#define PP 8732
#define NN 16
#define CC 81
#define IMG 300.0f
#define K2_BLOCKS 4096
#define K2_THREADS 64
#define TILE_ROWS 64
#define NT ((BB * PP) / TILE_ROWS)   // 17464 tiles, exact (no remainder)
#define K1_THREADS 512

// ---------------------------------------------------------------------------
// Kernel 1: per-image matching + bbox loss partials. (unchanged from round 3)
// grid = BB blocks, 512 threads
// ---------------------------------------------------------------------------
__global__ __launch_bounds__(K1_THREADS) void k1_match(
    const float* __restrict__ pred_boxes,   // [B,P,4]
    const float* __restrict__ tgt_boxes,    // [B,N,4] pixel cxcywh
    const int*   __restrict__ tgt_labels,   // [B,N]
    const float* __restrict__ dboxes,       // [P,4] cxcywh (clipped)
    int*   __restrict__ tlab_out,           // [B,P]
    float* __restrict__ bbox_partial,       // [B]
    int*   __restrict__ pos_count)          // [B]
{
    const int b   = blockIdx.x;
    const int tid = threadIdx.x;
    const int NW  = K1_THREADS / 64;

    __shared__ float t_cx[NN], t_cy[NN], t_w[NN], t_h[NN];
    __shared__ float t_x0s[NN], t_y0s[NN], t_x1s[NN], t_y1s[NN], t_areas[NN];
    __shared__ int   t_lab[NN];
    __shared__ unsigned short obj_s[PP];
    __shared__ unsigned char  chk_s[PP];
    __shared__ float red_v[NN][NW];
    __shared__ int   red_i[NN][NW];
    __shared__ int   box_idx_s[NN];
    __shared__ float red_f[NW];
    __shared__ int   red_c[NW];

    if (tid < NN) {
        const float* tb = tgt_boxes + ((size_t)b * NN + tid) * 4;
        float cx = tb[0] / IMG, cy = tb[1] / IMG, w = tb[2] / IMG, h = tb[3] / IMG;
        t_cx[tid] = cx; t_cy[tid] = cy; t_w[tid] = w; t_h[tid] = h;
        float x0 = cx - w * 0.5f, y0 = cy - h * 0.5f;
        float x1 = cx + w * 0.5f, y1 = cy + h * 0.5f;
        t_x0s[tid] = x0; t_y0s[tid] = y0; t_x1s[tid] = x1; t_y1s[tid] = y1;
        t_areas[tid] = (x1 - x0) * (y1 - y0);
        t_lab[tid] = tgt_labels[(size_t)b * NN + tid];
    }
    __syncthreads();

    float tx0[NN], ty0[NN], tx1[NN], ty1[NN], tar[NN];
#pragma unroll
    for (int n = 0; n < NN; ++n) {
        tx0[n] = t_x0s[n]; ty0[n] = t_y0s[n];
        tx1[n] = t_x1s[n]; ty1[n] = t_y1s[n];
        tar[n] = t_areas[n];
    }

    float bestv[NN];
    int   bestp[NN];
#pragma unroll
    for (int n = 0; n < NN; ++n) { bestv[n] = -1e30f; bestp[n] = 0x7fffffff; }

    for (int p = tid; p < PP; p += K1_THREADS) {
        float4 d = *reinterpret_cast<const float4*>(dboxes + (size_t)p * 4);
        float dx0 = d.x - d.z * 0.5f, dy0 = d.y - d.w * 0.5f;
        float dx1 = d.x + d.z * 0.5f, dy1 = d.y + d.w * 0.5f;
        float dar = (dx1 - dx0) * (dy1 - dy0);
        float bov = -1.0f; int bidx = 0;
#pragma unroll
        for (int n = 0; n < NN; ++n) {
            float lx = fmaxf(tx0[n], dx0);
            float ly = fmaxf(ty0[n], dy0);
            float rx = fminf(tx1[n], dx1);
            float ry = fminf(ty1[n], dy1);
            float iw = fmaxf(rx - lx, 0.0f);
            float ih = fmaxf(ry - ly, 0.0f);
            float inter = iw * ih;
            float iou = inter / (tar[n] + dar - inter);
            if (iou > bov) { bov = iou; bidx = n; }
            if (iou > bestv[n]) { bestv[n] = iou; bestp[n] = p; }
        }
        obj_s[p] = (unsigned short)bidx;
        chk_s[p] = (bov > 0.5f) ? 1 : 0;
    }

#pragma unroll
    for (int n = 0; n < NN; ++n) {
        float v = bestv[n]; int ip = bestp[n];
        for (int off = 32; off; off >>= 1) {
            float v2 = __shfl_xor(v, off);
            int   p2 = __shfl_xor(ip, off);
            if (v2 > v || (v2 == v && p2 < ip)) { v = v2; ip = p2; }
        }
        if ((tid & 63) == 0) { red_v[n][tid >> 6] = v; red_i[n][tid >> 6] = ip; }
    }
    __syncthreads();
    if (tid < NN) {
        float v = red_v[tid][0]; int ip = red_i[tid][0];
        for (int w = 1; w < NW; ++w) {
            float v2 = red_v[tid][w]; int p2 = red_i[tid][w];
            if (v2 > v || (v2 == v && p2 < ip)) { v = v2; ip = p2; }
        }
        box_idx_s[tid] = ip;
    }
    __syncthreads();
    if (tid == 0) {
        for (int n = 0; n < NN; ++n) obj_s[box_idx_s[n]] = (unsigned short)n;
    }
    __syncthreads();

    float bacc = 0.0f;
    int   pcnt = 0;
    for (int p = tid; p < PP; p += K1_THREADS) {
        int lab = 0;
        if (chk_s[p]) {
            int n = obj_s[p];
            lab = t_lab[n];
            if (lab != 0) {
                ++pcnt;
                float4 d = *reinterpret_cast<const float4*>(dboxes + (size_t)p * 4);
                float gx = (t_cx[n] - d.x) / (d.z / 10.0f);
                float gy = (t_cy[n] - d.y) / (d.w / 10.0f);
                float gw = logf(t_w[n] / d.z) * 5.0f;
                float gh = logf(t_h[n] / d.w) * 5.0f;
                float4 pv = *reinterpret_cast<const float4*>(pred_boxes + ((size_t)b * PP + p) * 4);
                float dfs[4] = { pv.x - gx, pv.y - gy, pv.z - gw, pv.w - gh };
#pragma unroll
                for (int j = 0; j < 4; ++j) {
                    float ad = fabsf(dfs[j]);
                    bacc += (ad < 1.0f) ? 0.5f * ad * ad : ad - 0.5f;
                }
            }
        }
        tlab_out[(size_t)b * PP + p] = lab;
    }
    for (int off = 32; off; off >>= 1) {
        bacc += __shfl_xor(bacc, off);
        pcnt += __shfl_xor(pcnt, off);
    }
    if ((tid & 63) == 0) { red_f[tid >> 6] = bacc; red_c[tid >> 6] = pcnt; }
    __syncthreads();
    if (tid == 0) {
        float s = 0.0f; int c = 0;
        for (int w = 0; w < NW; ++w) { s += red_f[w]; c += red_c[w]; }
        bbox_partial[b] = s;
        pos_count[b]    = c;
    }
}

// ---------------------------------------------------------------------------
// Kernel 2 (v3): one THREAD per row. 64-thread blocks stage 64 contiguous
// rows (20.7 KB linear copy, coalesced dword loads), then each lane serially
// reduces its own row from LDS (stride 81 words -> bank-bijective, 2-way
// aliasing only = free). Removes all softmax shuffles and cuts v_exp_f32
// wave-instructions ~4.3x vs the 16-lane version.
// grid = K2_BLOCKS x 64
// ---------------------------------------------------------------------------
__global__ __launch_bounds__(K2_THREADS) void k2_cls(
    const float* __restrict__ scores,  // [B*P, C]
    const int*   __restrict__ tlab,    // [B*P]
    float* __restrict__ neg,           // [B*P]
    float* __restrict__ clspos_partial)// [K2_BLOCKS]
{
    __shared__ float slds[TILE_ROWS * CC];   // 64 rows x 81 floats = 20736 B
    const int lane = threadIdx.x;
    float acc = 0.0f;

    for (int t = blockIdx.x; t < NT; t += gridDim.x) {
        const float* g = scores + (size_t)t * (TILE_ROWS * CC);
        __syncthreads();   // prior-iteration readers done before overwrite
        for (int i = lane; i < TILE_ROWS * CC; i += K2_THREADS)
            slds[i] = g[i];                   // linear, coalesced (256B/wave-instr)
        __syncthreads();

        const float* myrow = &slds[lane * CC];
        float m = myrow[0];
#pragma unroll 16
        for (int c = 1; c < CC; ++c) m = fmaxf(m, myrow[c]);
        float s = 0.0f;
#pragma unroll 16
        for (int c = 0; c < CC; ++c) s += __expf(myrow[c] - m);

        long long r = (long long)t * TILE_ROWS + lane;
        int   lab = tlab[r];                  // coalesced
        float cls = m + __logf(s) - myrow[lab];
        if (lab != 0) { acc += cls; neg[r] = 0.0f; }
        else          { neg[r] = cls; }
    }

    for (int off = 32; off; off >>= 1) acc += __shfl_xor(acc, off);
    if (lane == 0) clspos_partial[blockIdx.x] = acc;
}

// ---------------------------------------------------------------------------
// Kernel 3: exact radix select top-k sum. (unchanged from round 3)
// grid = BB x 256
// ---------------------------------------------------------------------------
__global__ __launch_bounds__(256) void k3_topk(
    const float* __restrict__ neg,
    const int*   __restrict__ pos_count,
    float* __restrict__ hard_partial)
{
    const int b   = blockIdx.x;
    const int tid = threadIdx.x;

    __shared__ unsigned int vals[PP];
    __shared__ int hist[256];
    __shared__ int scan[256];
    __shared__ unsigned int s_prefix;
    __shared__ int s_kk;
    __shared__ float wsum[4];

    for (int i = tid; i < PP; i += 256)
        vals[i] = __float_as_uint(neg[(size_t)b * PP + i]);

    int k = pos_count[b] * 3;
    if (k > PP) k = PP;
    if (k <= 0) {
        if (tid == 0) hard_partial[b] = 0.0f;
        return;
    }
    if (tid == 0) { s_prefix = 0u; s_kk = k; }
    __syncthreads();

    unsigned int prefmask = 0u;
    for (int round = 0; round < 4; ++round) {
        const int shift = 24 - 8 * round;
        hist[tid] = 0;
        __syncthreads();
        unsigned int pref = s_prefix;
        for (int i = tid; i < PP; i += 256) {
            unsigned int v = vals[i];
            if ((v & prefmask) == pref)
                atomicAdd(&hist[(v >> shift) & 0xFF], 1);
        }
        __syncthreads();
        scan[tid] = hist[tid];
        __syncthreads();
        for (int off = 1; off < 256; off <<= 1) {
            int add = (tid + off < 256) ? scan[tid + off] : 0;
            __syncthreads();
            scan[tid] += add;
            __syncthreads();
        }
        int sg = scan[tid] - hist[tid];
        int kk = s_kk;
        __syncthreads();
        if (sg < kk && sg + hist[tid] >= kk) {
            s_prefix = pref | ((unsigned int)tid << shift);
            s_kk     = kk - sg;
        }
        __syncthreads();
        prefmask |= (0xFFu << shift);
    }

    unsigned int t = s_prefix;
    int kk = s_kk;
    float tf = __uint_as_float(t);

    float acc = 0.0f;
    for (int i = tid; i < PP; i += 256) {
        unsigned int v = vals[i];
        if (v > t) acc += __uint_as_float(v);
    }
    for (int off = 32; off; off >>= 1) acc += __shfl_xor(acc, off);
    if ((tid & 63) == 0) wsum[tid >> 6] = acc;
    __syncthreads();
    if (tid == 0)
        hard_partial[b] = wsum[0] + wsum[1] + wsum[2] + wsum[3] + (float)kk * tf;
}

// ---------------------------------------------------------------------------
// Kernel 4: combine (unchanged)
// ---------------------------------------------------------------------------
__global__ __launch_bounds__(256) void k4_final(
    const float* __restrict__ clspos_partial,
    const float* __restrict__ bbox_partial,
    const float* __restrict__ hard_partial,
    const int*   __restrict__ pos_count,
    float* __restrict__ out)
{
    const int tid = threadIdx.x;
    float cacc = 0.0f, bacc = 0.0f, hacc = 0.0f;
    int   pacc = 0;
    for (int i = tid; i < K2_BLOCKS; i += 256) cacc += clspos_partial[i];
    if (tid < BB) {
        bacc = bbox_partial[tid];
        hacc = hard_partial[tid];
        pacc = pos_count[tid];
    }
    __shared__ float sc[256], sb[256], sh[256];
    __shared__ int   sp[256];
    sc[tid] = cacc; sb[tid] = bacc; sh[tid] = hacc; sp[tid] = pacc;
    __syncthreads();
    for (int off = 128; off; off >>= 1) {
        if (tid < off) {
            sc[tid] += sc[tid + off];
            sb[tid] += sb[tid + off];
            sh[tid] += sh[tid + off];
            sp[tid] += sp[tid + off];
        }
        __syncthreads();
    }
    if (tid == 0) {
        float npos = fmaxf((float)sp[0], 1.0f);
        out[0] = (sc[0] + sh[0]) / npos + sb[0] / (npos * 4.0f);
    }
}

// ---------------------------------------------------------------------------
extern "C" void kernel_launch(void* const* d_in, const int* in_sizes, int n_in,
                              void* d_out, int out_size, void* d_ws, size_t ws_size,
                              hipStream_t stream) {
    const float* pred_boxes  = (const float*)d_in[0];
    const float* pred_scores = (const float*)d_in[1];
    const float* tgt_boxes   = (const float*)d_in[2];
    const int*   tgt_labels  = (const int*)d_in[3];
    const float* dboxes      = (const float*)d_in[4];
    float* out = (float*)d_out;

    char* ws = (char*)d_ws;
    int*   tlab           = (int*)ws;   ws += (size_t)BB * PP * sizeof(int);
    float* neg            = (float*)ws; ws += (size_t)BB * PP * sizeof(float);
    int*   pos_count      = (int*)ws;   ws += BB * sizeof(int);
    float* bbox_partial   = (float*)ws; ws += BB * sizeof(float);
    float* hard_partial   = (float*)ws; ws += BB * sizeof(float);
    float* clspos_partial = (float*)ws; ws += K2_BLOCKS * sizeof(float);

    k1_match<<<BB, K1_THREADS, 0, stream>>>(pred_boxes, tgt_boxes, tgt_labels, dboxes,
                                            tlab, bbox_partial, pos_count);
    k2_cls<<<K2_BLOCKS, K2_THREADS, 0, stream>>>(pred_scores, tlab, neg, clspos_partial);
    k3_topk<<<BB, 256, 0, stream>>>(neg, pos_count, hard_partial);
    k4_final<<<1, 256, 0, stream>>>(clspos_partial, bbox_partial, hard_partial,
                                    pos_count, out);
}

// Round 5
// 159.489 us; speedup vs baseline: 1.3400x; 1.3400x over previous
//
#include <hip/hip_runtime.h>
#include <hip/hip_bf16.h>
#include <math.h>

#define BB 128
#define PP 8732
#define NN 16
#define CC 81
#define IMG 300.0f
#define TILE_ROWS 64
#define NT ((BB * PP) / TILE_ROWS)   // 17464 tiles, exact (1,117,696 rows)
#define K1_THREADS 512

// ---------------------------------------------------------------------------
// Kernel 1: per-image matching + bbox loss partials. (unchanged from round 3)
// grid = BB blocks, 512 threads
// ---------------------------------------------------------------------------
__global__ __launch_bounds__(K1_THREADS) void k1_match(
    const float* __restrict__ pred_boxes,   // [B,P,4]
    const float* __restrict__ tgt_boxes,    // [B,N,4] pixel cxcywh
    const int*   __restrict__ tgt_labels,   // [B,N]
    const float* __restrict__ dboxes,       // [P,4] cxcywh (clipped)
    int*   __restrict__ tlab_out,           // [B,P]
    float* __restrict__ bbox_partial,       // [B]
    int*   __restrict__ pos_count)          // [B]
{
    const int b   = blockIdx.x;
    const int tid = threadIdx.x;
    const int NW  = K1_THREADS / 64;

    __shared__ float t_cx[NN], t_cy[NN], t_w[NN], t_h[NN];
    __shared__ float t_x0s[NN], t_y0s[NN], t_x1s[NN], t_y1s[NN], t_areas[NN];
    __shared__ int   t_lab[NN];
    __shared__ unsigned short obj_s[PP];
    __shared__ unsigned char  chk_s[PP];
    __shared__ float red_v[NN][NW];
    __shared__ int   red_i[NN][NW];
    __shared__ int   box_idx_s[NN];
    __shared__ float red_f[NW];
    __shared__ int   red_c[NW];

    if (tid < NN) {
        const float* tb = tgt_boxes + ((size_t)b * NN + tid) * 4;
        float cx = tb[0] / IMG, cy = tb[1] / IMG, w = tb[2] / IMG, h = tb[3] / IMG;
        t_cx[tid] = cx; t_cy[tid] = cy; t_w[tid] = w; t_h[tid] = h;
        float x0 = cx - w * 0.5f, y0 = cy - h * 0.5f;
        float x1 = cx + w * 0.5f, y1 = cy + h * 0.5f;
        t_x0s[tid] = x0; t_y0s[tid] = y0; t_x1s[tid] = x1; t_y1s[tid] = y1;
        t_areas[tid] = (x1 - x0) * (y1 - y0);
        t_lab[tid] = tgt_labels[(size_t)b * NN + tid];
    }
    __syncthreads();

    float tx0[NN], ty0[NN], tx1[NN], ty1[NN], tar[NN];
#pragma unroll
    for (int n = 0; n < NN; ++n) {
        tx0[n] = t_x0s[n]; ty0[n] = t_y0s[n];
        tx1[n] = t_x1s[n]; ty1[n] = t_y1s[n];
        tar[n] = t_areas[n];
    }

    float bestv[NN];
    int   bestp[NN];
#pragma unroll
    for (int n = 0; n < NN; ++n) { bestv[n] = -1e30f; bestp[n] = 0x7fffffff; }

    for (int p = tid; p < PP; p += K1_THREADS) {
        float4 d = *reinterpret_cast<const float4*>(dboxes + (size_t)p * 4);
        float dx0 = d.x - d.z * 0.5f, dy0 = d.y - d.w * 0.5f;
        float dx1 = d.x + d.z * 0.5f, dy1 = d.y + d.w * 0.5f;
        float dar = (dx1 - dx0) * (dy1 - dy0);
        float bov = -1.0f; int bidx = 0;
#pragma unroll
        for (int n = 0; n < NN; ++n) {
            float lx = fmaxf(tx0[n], dx0);
            float ly = fmaxf(ty0[n], dy0);
            float rx = fminf(tx1[n], dx1);
            float ry = fminf(ty1[n], dy1);
            float iw = fmaxf(rx - lx, 0.0f);
            float ih = fmaxf(ry - ly, 0.0f);
            float inter = iw * ih;
            float iou = inter / (tar[n] + dar - inter);
            if (iou > bov) { bov = iou; bidx = n; }
            if (iou > bestv[n]) { bestv[n] = iou; bestp[n] = p; }
        }
        obj_s[p] = (unsigned short)bidx;
        chk_s[p] = (bov > 0.5f) ? 1 : 0;
    }

#pragma unroll
    for (int n = 0; n < NN; ++n) {
        float v = bestv[n]; int ip = bestp[n];
        for (int off = 32; off; off >>= 1) {
            float v2 = __shfl_xor(v, off);
            int   p2 = __shfl_xor(ip, off);
            if (v2 > v || (v2 == v && p2 < ip)) { v = v2; ip = p2; }
        }
        if ((tid & 63) == 0) { red_v[n][tid >> 6] = v; red_i[n][tid >> 6] = ip; }
    }
    __syncthreads();
    if (tid < NN) {
        float v = red_v[tid][0]; int ip = red_i[tid][0];
        for (int w = 1; w < NW; ++w) {
            float v2 = red_v[tid][w]; int p2 = red_i[tid][w];
            if (v2 > v || (v2 == v && p2 < ip)) { v = v2; ip = p2; }
        }
        box_idx_s[tid] = ip;
    }
    __syncthreads();
    if (tid == 0) {
        for (int n = 0; n < NN; ++n) obj_s[box_idx_s[n]] = (unsigned short)n;
    }
    __syncthreads();

    float bacc = 0.0f;
    int   pcnt = 0;
    for (int p = tid; p < PP; p += K1_THREADS) {
        int lab = 0;
        if (chk_s[p]) {
            int n = obj_s[p];
            lab = t_lab[n];
            if (lab != 0) {
                ++pcnt;
                float4 d = *reinterpret_cast<const float4*>(dboxes + (size_t)p * 4);
                float gx = (t_cx[n] - d.x) / (d.z / 10.0f);
                float gy = (t_cy[n] - d.y) / (d.w / 10.0f);
                float gw = logf(t_w[n] / d.z) * 5.0f;
                float gh = logf(t_h[n] / d.w) * 5.0f;
                float4 pv = *reinterpret_cast<const float4*>(pred_boxes + ((size_t)b * PP + p) * 4);
                float dfs[4] = { pv.x - gx, pv.y - gy, pv.z - gw, pv.w - gh };
#pragma unroll
                for (int j = 0; j < 4; ++j) {
                    float ad = fabsf(dfs[j]);
                    bacc += (ad < 1.0f) ? 0.5f * ad * ad : ad - 0.5f;
                }
            }
        }
        tlab_out[(size_t)b * PP + p] = lab;
    }
    for (int off = 32; off; off >>= 1) {
        bacc += __shfl_xor(bacc, off);
        pcnt += __shfl_xor(pcnt, off);
    }
    if ((tid & 63) == 0) { red_f[tid >> 6] = bacc; red_c[tid >> 6] = pcnt; }
    __syncthreads();
    if (tid == 0) {
        float s = 0.0f; int c = 0;
        for (int w = 0; w < NW; ++w) { s += red_f[w]; c += red_c[w]; }
        bbox_partial[b] = s;
        pos_count[b]    = c;
    }
}

// ---------------------------------------------------------------------------
// Kernel 2 (v4): one 64-row tile per 256-thread block, 4 threads per row.
// Fixes r4's traps: 28 waves/CU (vs 7) and 4-way ILP in the exp chain.
// Stage tile to LDS coalesced; each thread keeps its 20-21 row elements in
// REGISTERS (static unroll); max via 2 shfl_xor; partial sums with 4
// accumulators; combine via 2 shfl_xor. exp density 1.33 wave-instr/row,
// zero online-combine exps, no divergent global gathers (lab from LDS).
// grid = NT x 256
// ---------------------------------------------------------------------------
__global__ __launch_bounds__(256) void k2_cls(
    const float* __restrict__ scores,  // [B*P, C]
    const int*   __restrict__ tlab,    // [B*P]
    float* __restrict__ neg,           // [B*P]
    float* __restrict__ clspos_partial)// [NT]
{
    __shared__ float slds[TILE_ROWS * CC];   // 64 x 81 floats = 20736 B
    const int tid = threadIdx.x;
    const int t   = blockIdx.x;

    const float* g = scores + (size_t)t * (TILE_ROWS * CC);
    for (int i = tid; i < TILE_ROWS * CC; i += 256)
        slds[i] = g[i];                      // coalesced, 256B/wave-instr
    __syncthreads();

    const int row = tid >> 2;                // 0..63
    const int q   = tid & 3;                 // quarter of the row
    const float* myrow = &slds[row * CC];
    const int base = q * 20;

    // 20 elements (+1 for q==3) into registers, all static indexing
    float x[21];
#pragma unroll
    for (int i = 0; i < 20; ++i) x[i] = myrow[base + i];
    x[20] = (q == 3) ? myrow[80] : -1e30f;

    // row max: tree in registers, then across the 4 lanes
    float m = x[0];
#pragma unroll
    for (int i = 1; i < 21; ++i) m = fmaxf(m, x[i]);
    m = fmaxf(m, __shfl_xor(m, 1));
    m = fmaxf(m, __shfl_xor(m, 2));          // all 4 lanes now hold row max M

    // partial sum of exp(x - M), 4 independent accumulators (ILP)
    float s0 = 0.0f, s1 = 0.0f, s2 = 0.0f, s3 = 0.0f;
#pragma unroll
    for (int i = 0; i < 20; i += 4) {
        s0 += __expf(x[i + 0] - m);
        s1 += __expf(x[i + 1] - m);
        s2 += __expf(x[i + 2] - m);
        s3 += __expf(x[i + 3] - m);
    }
    s0 += __expf(x[20] - m);                 // pad lanes add exp(-huge) = 0
    float s = (s0 + s1) + (s2 + s3);
    s += __shfl_xor(s, 1);
    s += __shfl_xor(s, 2);                   // all 4 lanes hold row sum S

    float acc = 0.0f;
    if (q == 0) {
        long long r = (long long)t * TILE_ROWS + row;
        int   lab = tlab[r];                 // 16 lanes/wave, consecutive rows
        float cls = m + __logf(s) - slds[row * CC + lab];
        if (lab != 0) { acc = cls; neg[r] = 0.0f; }
        else          { neg[r] = cls; }
    }

    // block reduce acc (fixed topology)
    for (int off = 32; off; off >>= 1) acc += __shfl_xor(acc, off);
    __shared__ float wsum[4];
    if ((tid & 63) == 0) wsum[tid >> 6] = acc;
    __syncthreads();
    if (tid == 0)
        clspos_partial[t] = wsum[0] + wsum[1] + wsum[2] + wsum[3];
}

// ---------------------------------------------------------------------------
// Kernel 3: exact radix select top-k sum. (unchanged)
// grid = BB x 256
// ---------------------------------------------------------------------------
__global__ __launch_bounds__(256) void k3_topk(
    const float* __restrict__ neg,
    const int*   __restrict__ pos_count,
    float* __restrict__ hard_partial)
{
    const int b   = blockIdx.x;
    const int tid = threadIdx.x;

    __shared__ unsigned int vals[PP];
    __shared__ int hist[256];
    __shared__ int scan[256];
    __shared__ unsigned int s_prefix;
    __shared__ int s_kk;
    __shared__ float wsum[4];

    for (int i = tid; i < PP; i += 256)
        vals[i] = __float_as_uint(neg[(size_t)b * PP + i]);

    int k = pos_count[b] * 3;
    if (k > PP) k = PP;
    if (k <= 0) {
        if (tid == 0) hard_partial[b] = 0.0f;
        return;
    }
    if (tid == 0) { s_prefix = 0u; s_kk = k; }
    __syncthreads();

    unsigned int prefmask = 0u;
    for (int round = 0; round < 4; ++round) {
        const int shift = 24 - 8 * round;
        hist[tid] = 0;
        __syncthreads();
        unsigned int pref = s_prefix;
        for (int i = tid; i < PP; i += 256) {
            unsigned int v = vals[i];
            if ((v & prefmask) == pref)
                atomicAdd(&hist[(v >> shift) & 0xFF], 1);
        }
        __syncthreads();
        scan[tid] = hist[tid];
        __syncthreads();
        for (int off = 1; off < 256; off <<= 1) {
            int add = (tid + off < 256) ? scan[tid + off] : 0;
            __syncthreads();
            scan[tid] += add;
            __syncthreads();
        }
        int sg = scan[tid] - hist[tid];
        int kk = s_kk;
        __syncthreads();
        if (sg < kk && sg + hist[tid] >= kk) {
            s_prefix = pref | ((unsigned int)tid << shift);
            s_kk     = kk - sg;
        }
        __syncthreads();
        prefmask |= (0xFFu << shift);
    }

    unsigned int t = s_prefix;
    int kk = s_kk;
    float tf = __uint_as_float(t);

    float acc = 0.0f;
    for (int i = tid; i < PP; i += 256) {
        unsigned int v = vals[i];
        if (v > t) acc += __uint_as_float(v);
    }
    for (int off = 32; off; off >>= 1) acc += __shfl_xor(acc, off);
    if ((tid & 63) == 0) wsum[tid >> 6] = acc;
    __syncthreads();
    if (tid == 0)
        hard_partial[b] = wsum[0] + wsum[1] + wsum[2] + wsum[3] + (float)kk * tf;
}

// ---------------------------------------------------------------------------
// Kernel 4: combine (loops to NT now)
// ---------------------------------------------------------------------------
__global__ __launch_bounds__(256) void k4_final(
    const float* __restrict__ clspos_partial,
    const float* __restrict__ bbox_partial,
    const float* __restrict__ hard_partial,
    const int*   __restrict__ pos_count,
    float* __restrict__ out)
{
    const int tid = threadIdx.x;
    float cacc = 0.0f, bacc = 0.0f, hacc = 0.0f;
    int   pacc = 0;
    for (int i = tid; i < NT; i += 256) cacc += clspos_partial[i];
    if (tid < BB) {
        bacc = bbox_partial[tid];
        hacc = hard_partial[tid];
        pacc = pos_count[tid];
    }
    __shared__ float sc[256], sb[256], sh[256];
    __shared__ int   sp[256];
    sc[tid] = cacc; sb[tid] = bacc; sh[tid] = hacc; sp[tid] = pacc;
    __syncthreads();
    for (int off = 128; off; off >>= 1) {
        if (tid < off) {
            sc[tid] += sc[tid + off];
            sb[tid] += sb[tid + off];
            sh[tid] += sh[tid + off];
            sp[tid] += sp[tid + off];
        }
        __syncthreads();
    }
    if (tid == 0) {
        float npos = fmaxf((float)sp[0], 1.0f);
        out[0] = (sc[0] + sh[0]) / npos + sb[0] / (npos * 4.0f);
    }
}

// ---------------------------------------------------------------------------
extern "C" void kernel_launch(void* const* d_in, const int* in_sizes, int n_in,
                              void* d_out, int out_size, void* d_ws, size_t ws_size,
                              hipStream_t stream) {
    const float* pred_boxes  = (const float*)d_in[0];
    const float* pred_scores = (const float*)d_in[1];
    const float* tgt_boxes   = (const float*)d_in[2];
    const int*   tgt_labels  = (const int*)d_in[3];
    const float* dboxes      = (const float*)d_in[4];
    float* out = (float*)d_out;

    char* ws = (char*)d_ws;
    int*   tlab           = (int*)ws;   ws += (size_t)BB * PP * sizeof(int);
    float* neg            = (float*)ws; ws += (size_t)BB * PP * sizeof(float);
    int*   pos_count      = (int*)ws;   ws += BB * sizeof(int);
    float* bbox_partial   = (float*)ws; ws += BB * sizeof(float);
    float* hard_partial   = (float*)ws; ws += BB * sizeof(float);
    float* clspos_partial = (float*)ws; ws += (size_t)NT * sizeof(float);

    k1_match<<<BB, K1_THREADS, 0, stream>>>(pred_boxes, tgt_boxes, tgt_labels, dboxes,
                                            tlab, bbox_partial, pos_count);
    k2_cls<<<NT, 256, 0, stream>>>(pred_scores, tlab, neg, clspos_partial);
    k3_topk<<<BB, 256, 0, stream>>>(neg, pos_count, hard_partial);
    k4_final<<<1, 256, 0, stream>>>(clspos_partial, bbox_partial, hard_partial,
                                    pos_count, out);
}

// Round 6
// 158.247 us; speedup vs baseline: 1.3505x; 1.0078x over previous
//
#include <hip/hip_runtime.h>
#include <hip/hip_bf16.h>
#include <math.h>

#define BB 128
#define PP 8732
#define NN 16
#define CC 81
#define IMG 300.0f
#define TILE_ROWS 64
#define NT ((BB * PP) / TILE_ROWS)   // 17464 tiles, exact (1,117,696 rows)
#define K1_THREADS 512

// ---------------------------------------------------------------------------
// Kernel 1: per-image matching + bbox loss partials. (unchanged from round 3)
// grid = BB blocks, 512 threads
// ---------------------------------------------------------------------------
__global__ __launch_bounds__(K1_THREADS) void k1_match(
    const float* __restrict__ pred_boxes,   // [B,P,4]
    const float* __restrict__ tgt_boxes,    // [B,N,4] pixel cxcywh
    const int*   __restrict__ tgt_labels,   // [B,N]
    const float* __restrict__ dboxes,       // [P,4] cxcywh (clipped)
    int*   __restrict__ tlab_out,           // [B,P]
    float* __restrict__ bbox_partial,       // [B]
    int*   __restrict__ pos_count)          // [B]
{
    const int b   = blockIdx.x;
    const int tid = threadIdx.x;
    const int NW  = K1_THREADS / 64;

    __shared__ float t_cx[NN], t_cy[NN], t_w[NN], t_h[NN];
    __shared__ float t_x0s[NN], t_y0s[NN], t_x1s[NN], t_y1s[NN], t_areas[NN];
    __shared__ int   t_lab[NN];
    __shared__ unsigned short obj_s[PP];
    __shared__ unsigned char  chk_s[PP];
    __shared__ float red_v[NN][NW];
    __shared__ int   red_i[NN][NW];
    __shared__ int   box_idx_s[NN];
    __shared__ float red_f[NW];
    __shared__ int   red_c[NW];

    if (tid < NN) {
        const float* tb = tgt_boxes + ((size_t)b * NN + tid) * 4;
        float cx = tb[0] / IMG, cy = tb[1] / IMG, w = tb[2] / IMG, h = tb[3] / IMG;
        t_cx[tid] = cx; t_cy[tid] = cy; t_w[tid] = w; t_h[tid] = h;
        float x0 = cx - w * 0.5f, y0 = cy - h * 0.5f;
        float x1 = cx + w * 0.5f, y1 = cy + h * 0.5f;
        t_x0s[tid] = x0; t_y0s[tid] = y0; t_x1s[tid] = x1; t_y1s[tid] = y1;
        t_areas[tid] = (x1 - x0) * (y1 - y0);
        t_lab[tid] = tgt_labels[(size_t)b * NN + tid];
    }
    __syncthreads();

    float tx0[NN], ty0[NN], tx1[NN], ty1[NN], tar[NN];
#pragma unroll
    for (int n = 0; n < NN; ++n) {
        tx0[n] = t_x0s[n]; ty0[n] = t_y0s[n];
        tx1[n] = t_x1s[n]; ty1[n] = t_y1s[n];
        tar[n] = t_areas[n];
    }

    float bestv[NN];
    int   bestp[NN];
#pragma unroll
    for (int n = 0; n < NN; ++n) { bestv[n] = -1e30f; bestp[n] = 0x7fffffff; }

    for (int p = tid; p < PP; p += K1_THREADS) {
        float4 d = *reinterpret_cast<const float4*>(dboxes + (size_t)p * 4);
        float dx0 = d.x - d.z * 0.5f, dy0 = d.y - d.w * 0.5f;
        float dx1 = d.x + d.z * 0.5f, dy1 = d.y + d.w * 0.5f;
        float dar = (dx1 - dx0) * (dy1 - dy0);
        float bov = -1.0f; int bidx = 0;
#pragma unroll
        for (int n = 0; n < NN; ++n) {
            float lx = fmaxf(tx0[n], dx0);
            float ly = fmaxf(ty0[n], dy0);
            float rx = fminf(tx1[n], dx1);
            float ry = fminf(ty1[n], dy1);
            float iw = fmaxf(rx - lx, 0.0f);
            float ih = fmaxf(ry - ly, 0.0f);
            float inter = iw * ih;
            float iou = inter / (tar[n] + dar - inter);
            if (iou > bov) { bov = iou; bidx = n; }
            if (iou > bestv[n]) { bestv[n] = iou; bestp[n] = p; }
        }
        obj_s[p] = (unsigned short)bidx;
        chk_s[p] = (bov > 0.5f) ? 1 : 0;
    }

#pragma unroll
    for (int n = 0; n < NN; ++n) {
        float v = bestv[n]; int ip = bestp[n];
        for (int off = 32; off; off >>= 1) {
            float v2 = __shfl_xor(v, off);
            int   p2 = __shfl_xor(ip, off);
            if (v2 > v || (v2 == v && p2 < ip)) { v = v2; ip = p2; }
        }
        if ((tid & 63) == 0) { red_v[n][tid >> 6] = v; red_i[n][tid >> 6] = ip; }
    }
    __syncthreads();
    if (tid < NN) {
        float v = red_v[tid][0]; int ip = red_i[tid][0];
        for (int w = 1; w < NW; ++w) {
            float v2 = red_v[tid][w]; int p2 = red_i[tid][w];
            if (v2 > v || (v2 == v && p2 < ip)) { v = v2; ip = p2; }
        }
        box_idx_s[tid] = ip;
    }
    __syncthreads();
    if (tid == 0) {
        for (int n = 0; n < NN; ++n) obj_s[box_idx_s[n]] = (unsigned short)n;
    }
    __syncthreads();

    float bacc = 0.0f;
    int   pcnt = 0;
    for (int p = tid; p < PP; p += K1_THREADS) {
        int lab = 0;
        if (chk_s[p]) {
            int n = obj_s[p];
            lab = t_lab[n];
            if (lab != 0) {
                ++pcnt;
                float4 d = *reinterpret_cast<const float4*>(dboxes + (size_t)p * 4);
                float gx = (t_cx[n] - d.x) / (d.z / 10.0f);
                float gy = (t_cy[n] - d.y) / (d.w / 10.0f);
                float gw = logf(t_w[n] / d.z) * 5.0f;
                float gh = logf(t_h[n] / d.w) * 5.0f;
                float4 pv = *reinterpret_cast<const float4*>(pred_boxes + ((size_t)b * PP + p) * 4);
                float dfs[4] = { pv.x - gx, pv.y - gy, pv.z - gw, pv.w - gh };
#pragma unroll
                for (int j = 0; j < 4; ++j) {
                    float ad = fabsf(dfs[j]);
                    bacc += (ad < 1.0f) ? 0.5f * ad * ad : ad - 0.5f;
                }
            }
        }
        tlab_out[(size_t)b * PP + p] = lab;
    }
    for (int off = 32; off; off >>= 1) {
        bacc += __shfl_xor(bacc, off);
        pcnt += __shfl_xor(pcnt, off);
    }
    if ((tid & 63) == 0) { red_f[tid >> 6] = bacc; red_c[tid >> 6] = pcnt; }
    __syncthreads();
    if (tid == 0) {
        float s = 0.0f; int c = 0;
        for (int w = 0; w < NW; ++w) { s += red_f[w]; c += red_c[w]; }
        bbox_partial[b] = s;
        pos_count[b]    = c;
    }
}

// ---------------------------------------------------------------------------
// Kernel 2 (v4): one 64-row tile per 256-thread block, 4 threads per row.
// (unchanged from round 5)
// grid = NT x 256
// ---------------------------------------------------------------------------
__global__ __launch_bounds__(256) void k2_cls(
    const float* __restrict__ scores,  // [B*P, C]
    const int*   __restrict__ tlab,    // [B*P]
    float* __restrict__ neg,           // [B*P]
    float* __restrict__ clspos_partial)// [NT]
{
    __shared__ float slds[TILE_ROWS * CC];   // 64 x 81 floats = 20736 B
    const int tid = threadIdx.x;
    const int t   = blockIdx.x;

    const float* g = scores + (size_t)t * (TILE_ROWS * CC);
    for (int i = tid; i < TILE_ROWS * CC; i += 256)
        slds[i] = g[i];                      // coalesced, 256B/wave-instr
    __syncthreads();

    const int row = tid >> 2;                // 0..63
    const int q   = tid & 3;                 // quarter of the row
    const float* myrow = &slds[row * CC];
    const int base = q * 20;

    float x[21];
#pragma unroll
    for (int i = 0; i < 20; ++i) x[i] = myrow[base + i];
    x[20] = (q == 3) ? myrow[80] : -1e30f;

    float m = x[0];
#pragma unroll
    for (int i = 1; i < 21; ++i) m = fmaxf(m, x[i]);
    m = fmaxf(m, __shfl_xor(m, 1));
    m = fmaxf(m, __shfl_xor(m, 2));          // all 4 lanes hold row max M

    float s0 = 0.0f, s1 = 0.0f, s2 = 0.0f, s3 = 0.0f;
#pragma unroll
    for (int i = 0; i < 20; i += 4) {
        s0 += __expf(x[i + 0] - m);
        s1 += __expf(x[i + 1] - m);
        s2 += __expf(x[i + 2] - m);
        s3 += __expf(x[i + 3] - m);
    }
    s0 += __expf(x[20] - m);
    float s = (s0 + s1) + (s2 + s3);
    s += __shfl_xor(s, 1);
    s += __shfl_xor(s, 2);                   // all 4 lanes hold row sum S

    float acc = 0.0f;
    if (q == 0) {
        long long r = (long long)t * TILE_ROWS + row;
        int   lab = tlab[r];
        float cls = m + __logf(s) - slds[row * CC + lab];
        if (lab != 0) { acc = cls; neg[r] = 0.0f; }
        else          { neg[r] = cls; }
    }

    for (int off = 32; off; off >>= 1) acc += __shfl_xor(acc, off);
    __shared__ float wsum[4];
    if ((tid & 63) == 0) wsum[tid >> 6] = acc;
    __syncthreads();
    if (tid == 0)
        clspos_partial[t] = wsum[0] + wsum[1] + wsum[2] + wsum[3];
}

// ---------------------------------------------------------------------------
// Kernel 3 (v3): exact radix select top-k sum with 32-REPLICA histogram.
// histR[rep][bin] padded to 257 so bank = (rep+bin)%32: concentrated-bin
// atomics spread over all 32 banks, <=2 lanes/replica -> ~conflict-free,
// removing the 64-way intra-wave same-address serialization of rounds 0-1.
// grid = BB x 256
// ---------------------------------------------------------------------------
#define HREP 32
#define HPAD 257
__global__ __launch_bounds__(256) void k3_topk(
    const float* __restrict__ neg,
    const int*   __restrict__ pos_count,
    float* __restrict__ hard_partial)
{
    const int b   = blockIdx.x;
    const int tid = threadIdx.x;
    const int rep = (tid & 63) >> 1;          // lane/2: 32 replicas, 2 lanes each

    __shared__ unsigned int vals[PP];         // 34928 B
    __shared__ int histR[HREP * HPAD];        // 32896 B
    __shared__ int scn[256];
    __shared__ unsigned int s_prefix;
    __shared__ int s_kk;
    __shared__ float wsum[4];

    for (int i = tid; i < PP; i += 256)
        vals[i] = __float_as_uint(neg[(size_t)b * PP + i]);

    int k = pos_count[b] * 3;
    if (k > PP) k = PP;
    if (k <= 0) {
        if (tid == 0) hard_partial[b] = 0.0f;
        return;
    }
    if (tid == 0) { s_prefix = 0u; s_kk = k; }
    __syncthreads();

    unsigned int prefmask = 0u;
    for (int round = 0; round < 4; ++round) {
        const int shift = 24 - 8 * round;
        for (int i = tid; i < HREP * HPAD; i += 256) histR[i] = 0;
        __syncthreads();                       // publishes s_prefix/s_kk + zeroed hist
        unsigned int pref = s_prefix;
        for (int i = tid; i < PP; i += 256) {
            unsigned int v = vals[i];
            if ((v & prefmask) == pref)
                atomicAdd(&histR[rep * HPAD + ((v >> shift) & 0xFF)], 1);
        }
        __syncthreads();
        int myh = 0;
#pragma unroll 8
        for (int r = 0; r < HREP; ++r) myh += histR[r * HPAD + tid];
        scn[tid] = myh;
        __syncthreads();
        for (int off = 1; off < 256; off <<= 1) {
            int add = (tid + off < 256) ? scn[tid + off] : 0;
            __syncthreads();
            scn[tid] += add;                   // suffix (descending) inclusive scan
            __syncthreads();
        }
        int sg = scn[tid] - myh;               // count strictly greater than bin tid
        int kk = s_kk;
        __syncthreads();                       // all kk reads done before write
        if (sg < kk && sg + myh >= kk) {       // exactly one bin satisfies
            s_prefix = pref | ((unsigned int)tid << shift);
            s_kk     = kk - sg;
        }
        __syncthreads();
        prefmask |= (0xFFu << shift);
    }

    unsigned int t = s_prefix;   // exact bits of k-th largest value
    int kk = s_kk;               // # of t-valued entries inside top-k
    float tf = __uint_as_float(t);

    float acc = 0.0f;
    for (int i = tid; i < PP; i += 256) {
        unsigned int v = vals[i];
        if (v > t) acc += __uint_as_float(v);
    }
    for (int off = 32; off; off >>= 1) acc += __shfl_xor(acc, off);
    if ((tid & 63) == 0) wsum[tid >> 6] = acc;
    __syncthreads();
    if (tid == 0)
        hard_partial[b] = wsum[0] + wsum[1] + wsum[2] + wsum[3] + (float)kk * tf;
}

// ---------------------------------------------------------------------------
// Kernel 4: combine (unchanged)
// ---------------------------------------------------------------------------
__global__ __launch_bounds__(256) void k4_final(
    const float* __restrict__ clspos_partial,
    const float* __restrict__ bbox_partial,
    const float* __restrict__ hard_partial,
    const int*   __restrict__ pos_count,
    float* __restrict__ out)
{
    const int tid = threadIdx.x;
    float cacc = 0.0f, bacc = 0.0f, hacc = 0.0f;
    int   pacc = 0;
    for (int i = tid; i < NT; i += 256) cacc += clspos_partial[i];
    if (tid < BB) {
        bacc = bbox_partial[tid];
        hacc = hard_partial[tid];
        pacc = pos_count[tid];
    }
    __shared__ float sc[256], sb[256], sh[256];
    __shared__ int   sp[256];
    sc[tid] = cacc; sb[tid] = bacc; sh[tid] = hacc; sp[tid] = pacc;
    __syncthreads();
    for (int off = 128; off; off >>= 1) {
        if (tid < off) {
            sc[tid] += sc[tid + off];
            sb[tid] += sb[tid + off];
            sh[tid] += sh[tid + off];
            sp[tid] += sp[tid + off];
        }
        __syncthreads();
    }
    if (tid == 0) {
        float npos = fmaxf((float)sp[0], 1.0f);
        out[0] = (sc[0] + sh[0]) / npos + sb[0] / (npos * 4.0f);
    }
}

// ---------------------------------------------------------------------------
extern "C" void kernel_launch(void* const* d_in, const int* in_sizes, int n_in,
                              void* d_out, int out_size, void* d_ws, size_t ws_size,
                              hipStream_t stream) {
    const float* pred_boxes  = (const float*)d_in[0];
    const float* pred_scores = (const float*)d_in[1];
    const float* tgt_boxes   = (const float*)d_in[2];
    const int*   tgt_labels  = (const int*)d_in[3];
    const float* dboxes      = (const float*)d_in[4];
    float* out = (float*)d_out;

    char* ws = (char*)d_ws;
    int*   tlab           = (int*)ws;   ws += (size_t)BB * PP * sizeof(int);
    float* neg            = (float*)ws; ws += (size_t)BB * PP * sizeof(float);
    int*   pos_count      = (int*)ws;   ws += BB * sizeof(int);
    float* bbox_partial   = (float*)ws; ws += BB * sizeof(float);
    float* hard_partial   = (float*)ws; ws += BB * sizeof(float);
    float* clspos_partial = (float*)ws; ws += (size_t)NT * sizeof(float);

    k1_match<<<BB, K1_THREADS, 0, stream>>>(pred_boxes, tgt_boxes, tgt_labels, dboxes,
                                            tlab, bbox_partial, pos_count);
    k2_cls<<<NT, 256, 0, stream>>>(pred_scores, tlab, neg, clspos_partial);
    k3_topk<<<BB, 256, 0, stream>>>(neg, pos_count, hard_partial);
    k4_final<<<1, 256, 0, stream>>>(clspos_partial, bbox_partial, hard_partial,
                                    pos_count, out);
}